// Round 5
// baseline (196.927 us; speedup 1.0000x reference)
//
#include <hip/hip_runtime.h>

#define N_ 4096
#define C_ 256
#define H_ 16
#define D_ 64
#define HD_ 1024

typedef __attribute__((ext_vector_type(8))) __bf16 bf16x8;
typedef __attribute__((ext_vector_type(4))) __bf16 bf16x4;
typedef __attribute__((ext_vector_type(8))) _Float16 f16x8;
typedef __attribute__((ext_vector_type(4))) _Float16 f16x4;
typedef __attribute__((ext_vector_type(4))) float f32x4;

__device__ __forceinline__ void gload16(const void* g, void* l) {
    __builtin_amdgcn_global_load_lds(
        (const __attribute__((address_space(1))) unsigned int*)g,
        (__attribute__((address_space(3))) unsigned int*)l, 16, 0, 0);
}

struct bf2 { __bf16 h, l; };
__device__ __forceinline__ bf2 split_bf16(float v) {
    bf2 r;
    r.h = (__bf16)v;
    r.l = (__bf16)(v - (float)r.h);
    return r;
}

// ---------------------------------------------------------------------------
// Kernel 0: convert fp32 inputs to bf16 hi/lo (X as-is, W transposed so the
// MFMA B-operand reads K-contiguous).
// ---------------------------------------------------------------------------
__global__ __launch_bounds__(256) void convert_kernel(
    const float* __restrict__ q_x, const float* __restrict__ kv_x,
    const float* __restrict__ Wq, const float* __restrict__ Wk,
    const float* __restrict__ Wv, const float* __restrict__ Wg,
    const float* __restrict__ Wo,
    __bf16* __restrict__ Xh, __bf16* __restrict__ Xl,
    __bf16* __restrict__ WTh, __bf16* __restrict__ WTl,
    __bf16* __restrict__ WoTh, __bf16* __restrict__ WoTl)
{
    __shared__ float ts[64][65];
    const int b = blockIdx.x;
    const int tid = threadIdx.x;

    if (b < 512) {
        const int seg = b >> 8;
        const float* src = seg ? kv_x : q_x;
        __bf16* dh = Xh + (size_t)seg * 1048576;
        __bf16* dl = Xl + (size_t)seg * 1048576;
        const int base = (b & 255) * 4096 + tid * 16;
#pragma unroll
        for (int q = 0; q < 4; ++q) {
            float4 v = *(const float4*)&src[base + q * 4];
            bf16x4 hv, lv;
            bf2 s0 = split_bf16(v.x); hv[0] = s0.h; lv[0] = s0.l;
            bf2 s1 = split_bf16(v.y); hv[1] = s1.h; lv[1] = s1.l;
            bf2 s2 = split_bf16(v.z); hv[2] = s2.h; lv[2] = s2.l;
            bf2 s3 = split_bf16(v.w); hv[3] = s3.h; lv[3] = s3.l;
            *(bf16x4*)&dh[base + q * 4] = hv;
            *(bf16x4*)&dl[base + q * 4] = lv;
        }
        return;
    }

    const float* src;
    __bf16 *dh, *dl;
    int srcC, dstC, r0, c0;
    if (b < 768) {
        const int widx = (b - 512) >> 6;
        const int tile = (b - 512) & 63;
        src = (widx == 0) ? Wq : (widx == 1) ? Wk : (widx == 2) ? Wv : Wg;
        dh = WTh + (size_t)widx * 262144;
        dl = WTl + (size_t)widx * 262144;
        srcC = 1024; dstC = 256;
        r0 = (tile >> 4) * 64;
        c0 = (tile & 15) * 64;
    } else {
        const int tile = b - 768;
        src = Wo; dh = WoTh; dl = WoTl;
        srcC = 256; dstC = 1024;
        r0 = (tile >> 2) * 64;
        c0 = (tile & 3) * 64;
    }
    {
        const int r = tid >> 2;
        const int cch = (tid & 3) * 16;
#pragma unroll
        for (int q = 0; q < 4; ++q) {
            float4 v = *(const float4*)&src[(size_t)(r0 + r) * srcC + c0 + cch + q * 4];
            ts[r][cch + q * 4 + 0] = v.x;
            ts[r][cch + q * 4 + 1] = v.y;
            ts[r][cch + q * 4 + 2] = v.z;
            ts[r][cch + q * 4 + 3] = v.w;
        }
    }
    __syncthreads();
    {
        const int c = tid >> 2;
        const int rch = (tid & 3) * 16;
#pragma unroll
        for (int q = 0; q < 4; ++q) {
            bf16x4 hv, lv;
#pragma unroll
            for (int j = 0; j < 4; ++j) {
                bf2 s = split_bf16(ts[rch + q * 4 + j][c]);
                hv[j] = s.h; lv[j] = s.l;
            }
            *(bf16x4*)&dh[(size_t)(c0 + c) * dstC + r0 + rch + q * 4] = hv;
            *(bf16x4*)&dl[(size_t)(c0 + c) * dstC + r0 + rch + q * 4] = lv;
        }
    }
}

// ---------------------------------------------------------------------------
// Kernel 1: projections via split-bf16 MFMA.
// XCD swizzle: all 8 col-tiles of one (gemm,row-tile) share xcd = lb&7, so
// the A row-slice is fetched into that XCD's L2 once (was: 8 XCDs x 8 MB).
// Epilogue: acc -> LDS fp16 (stride 132, conflict-free) -> f16x8 stores.
// ---------------------------------------------------------------------------
__global__ __launch_bounds__(256) void proj_mfma(
    const __bf16* __restrict__ Xh, const __bf16* __restrict__ Xl,
    const __bf16* __restrict__ WTh, const __bf16* __restrict__ WTl,
    _Float16* __restrict__ qh, _Float16* __restrict__ kh,
    _Float16* __restrict__ vh, _Float16* __restrict__ gh)
{
    __shared__ __align__(16) __bf16 smem[4 * 4096];
    __bf16* As_h = smem;
    __bf16* As_l = smem + 4096;
    __bf16* Bs_h = smem + 8192;
    __bf16* Bs_l = smem + 12288;

    // XCD-aware remap: xcd = lb&7 constant within a (g,row) group of 8 cols
    const int lb  = blockIdx.x;
    const int xcd = lb & 7;
    const int idx = lb >> 3;
    const int gr  = (idx >> 3) * 8 + xcd;   // 0..127 -> (g, row-tile)
    const int g   = gr >> 5;
    const int m0  = (gr & 31) * 128;
    const int c0  = (idx & 7) * 128;

    const size_t xoff = (g == 1 || g == 2) ? 1048576 : 0;
    const __bf16* Ah = Xh + xoff;
    const __bf16* Al = Xl + xoff;
    const __bf16* Bh = WTh + (size_t)g * 262144;
    const __bf16* Bl = WTl + (size_t)g * 262144;

    const int tid  = threadIdx.x;
    const int wave = tid >> 6;
    const int lane = tid & 63;
    const int wr   = wave >> 1;
    const int wc   = wave & 1;

    const int srow = tid >> 2;
    const int selem = (tid & 3) * 8;
    const int sbyte = tid * 16;

    f32x4 acc[4][4];
#pragma unroll
    for (int i = 0; i < 4; ++i)
#pragma unroll
        for (int j = 0; j < 4; ++j) acc[i][j] = (f32x4){0.f, 0.f, 0.f, 0.f};

    const int frow = lane & 15;
    const int fk   = (lane >> 4) * 8;

    for (int kt = 0; kt < 256; kt += 32) {
        __syncthreads();
#pragma unroll
        for (int p = 0; p < 2; ++p) {
            const int r = srow + p * 64;
            gload16(Ah + (size_t)(m0 + r) * 256 + kt + selem, (char*)As_h + p * 4096 + sbyte);
            gload16(Al + (size_t)(m0 + r) * 256 + kt + selem, (char*)As_l + p * 4096 + sbyte);
            gload16(Bh + (size_t)(c0 + r) * 256 + kt + selem, (char*)Bs_h + p * 4096 + sbyte);
            gload16(Bl + (size_t)(c0 + r) * 256 + kt + selem, (char*)Bs_l + p * 4096 + sbyte);
        }
        __syncthreads();

        bf16x8 afh[4], afl[4], bfh[4], bfl[4];
#pragma unroll
        for (int f = 0; f < 4; ++f) {
            const int ar = (wr * 64 + f * 16 + frow) * 32 + fk;
            const int br = (wc * 64 + f * 16 + frow) * 32 + fk;
            afh[f] = *(const bf16x8*)&As_h[ar];
            afl[f] = *(const bf16x8*)&As_l[ar];
            bfh[f] = *(const bf16x8*)&Bs_h[br];
            bfl[f] = *(const bf16x8*)&Bs_l[br];
        }
#pragma unroll
        for (int i = 0; i < 4; ++i)
#pragma unroll
            for (int j = 0; j < 4; ++j) {
                acc[i][j] = __builtin_amdgcn_mfma_f32_16x16x32_bf16(afh[i], bfh[j], acc[i][j], 0, 0, 0);
                acc[i][j] = __builtin_amdgcn_mfma_f32_16x16x32_bf16(afl[i], bfh[j], acc[i][j], 0, 0, 0);
                acc[i][j] = __builtin_amdgcn_mfma_f32_16x16x32_bf16(afh[i], bfl[j], acc[i][j], 0, 0, 0);
            }
    }

    // ---- epilogue via LDS: two 64-row phases, vectorized fp16 stores ----
    _Float16* Os = (_Float16*)smem;          // [64][132] = 16896 B
    const int rbase = (lane >> 4) * 4;
    const int colc  = lane & 15;
    const float scale = (g == 0) ? 0.125f : 1.f;
    const int er   = tid >> 2;               // 0..63: output row within phase
    const int eseg = tid & 3;                // 0..3: 32-col segment

    for (int p = 0; p < 2; ++p) {
        __syncthreads();                     // LDS free (K-loop / prev phase reads done)
        if (wr == p) {
#pragma unroll
            for (int i = 0; i < 4; ++i)
#pragma unroll
                for (int j = 0; j < 4; ++j) {
                    const int rr = i * 16 + rbase;
                    const int cc = wc * 64 + j * 16 + colc;
#pragma unroll
                    for (int v = 0; v < 4; ++v) {
                        float x = acc[i][j][v];
                        x = (g == 3) ? 1.f / (1.f + __expf(-x)) : x * scale;
                        Os[(rr + v) * 132 + cc] = (_Float16)x;
                    }
                }
        }
        __syncthreads();
        const int n = m0 + p * 64 + er;
        __align__(16) _Float16 buf[32];
#pragma unroll
        for (int e = 0; e < 32; e += 4)
            *(f16x4*)&buf[e] = *(const f16x4*)&Os[er * 132 + eseg * 32 + e];
        if (g == 3) {
            _Float16* dstp = gh + (size_t)n * HD_ + c0 + eseg * 32;
#pragma unroll
            for (int e = 0; e < 32; e += 8)
                *(f16x8*)&dstp[e] = *(const f16x8*)&buf[e];
        } else {
            _Float16* dst = (g == 0) ? qh : (g == 1) ? kh : vh;
            const int cglob = c0 + eseg * 32;
            const int hh = cglob >> 6, dd = cglob & 63;
            _Float16* dstp = dst + ((size_t)hh * N_ + n) * D_ + dd;
#pragma unroll
            for (int e = 0; e < 32; e += 8)
                *(f16x8*)&dstp[e] = *(const f16x8*)&buf[e];
        }
    }
}

// ---------------------------------------------------------------------------
// Kernel 2: local attention via fp16 MFMA. One block per (h,t), 4 waves.
// XCD swizzle: trunks t in [8*xcd, 8*xcd+8) x all heads on one XCD, so the
// k/v halo band and bias slices stay resident in that XCD's L2.
// ---------------------------------------------------------------------------
__global__ __launch_bounds__(256) void attn_mfma(
    const _Float16* __restrict__ qh, const _Float16* __restrict__ kh,
    const _Float16* __restrict__ vh, const float* __restrict__ bias,
    const _Float16* __restrict__ gh,
    __bf16* __restrict__ o_hi, __bf16* __restrict__ o_lo)
{
    __shared__ __align__(16) char smem[59392];
    _Float16* Qs = (_Float16*)smem;              // [64][64], swizzled chunks, 8 KB
    char* Ks = smem + 8192;                      // K: [128][64] swizzled, 16 KB
    _Float16* Vs = (_Float16*)(smem + 8192);     // V^T: [64][136], 17408 B (overlays Ks)
    _Float16* Ps = (_Float16*)(smem + 25600);    // [64][264], 33792 B

    const int lb  = blockIdx.x;
    const int xcd = lb & 7;
    const int j_  = lb >> 3;
    const int h   = j_ >> 3;                // 0..15
    const int t   = xcd * 8 + (j_ & 7);     // 0..63, 8 consecutive t per XCD
    const int tid = threadIdx.x;
    const int lane = tid & 63;
    const int wv = tid >> 6;
    const int frow = lane & 15;
    const int grp = lane >> 4;
    const int kbase = t * 64 - 96;

    const char* qbase = (const char*)qh + (size_t)(h * N_ + t * 64) * 128;
    const char* kbase_p = (const char*)kh + (size_t)h * N_ * 128;

    // ---- stage Q (8 KB, always in-bounds), issue async ----
#pragma unroll
    for (int q = 0; q < 2; ++q) {
        const int lin = q * 4096 + tid * 16;
        const int row = lin >> 7;
        const int ch = (lin >> 4) & 7;
        gload16(qbase + row * 128 + ((ch ^ (row & 7)) << 4), (char*)Qs + lin);
    }

    f32x4 sacc[16];

#pragma unroll
    for (int p = 0; p < 2; ++p) {
        // stage K chunk p (16 KB); OOB rows -> zero (wave-uniform split)
#pragma unroll
        for (int q = 0; q < 4; ++q) {
            const int lin = q * 4096 + tid * 16;
            const int row = lin >> 7;
            const int ch = (lin >> 4) & 7;
            const int kg = kbase + p * 128 + row;
            if ((unsigned)kg < (unsigned)N_) {
                gload16(kbase_p + (size_t)kg * 128 + ((ch ^ (row & 7)) << 4), Ks + lin);
            } else {
                *(float4*)(Ks + lin) = make_float4(0.f, 0.f, 0.f, 0.f);
            }
        }
        // bias -> accumulator init for this chunk
        {
            const int rowg = t * 64 + wv * 16 + grp * 4;
#pragma unroll
            for (int j = 0; j < 8; ++j) {
                const int colg = kbase + p * 128 + j * 16 + frow;
                const bool ok = (unsigned)colg < (unsigned)N_;
#pragma unroll
                for (int v = 0; v < 4; ++v)
                    sacc[p * 8 + j][v] = ok ? bias[(size_t)(rowg + v) * N_ + colg] : 0.f;
            }
        }
        __syncthreads();   // staging complete (Q covered at p=0)
        const int rq = wv * 16 + frow;
#pragma unroll
        for (int ks = 0; ks < 2; ++ks) {
            const f16x8 aq = *(const f16x8*)((char*)Qs + rq * 128 + (((ks * 4 + grp) ^ (rq & 7)) << 4));
#pragma unroll
            for (int j = 0; j < 8; ++j) {
                const int rk = j * 16 + frow;
                const f16x8 bk = *(const f16x8*)(Ks + rk * 128 + (((ks * 4 + grp) ^ (rk & 7)) << 4));
                sacc[p * 8 + j] = __builtin_amdgcn_mfma_f32_16x16x32_f16(aq, bk, sacc[p * 8 + j], 0, 0, 0);
            }
        }
        __syncthreads();   // K reads done before restage/overlay
    }

    // ---- softmax over 256 slots/row; rows owned per (grp, v) ----
    float inv[4];
#pragma unroll
    for (int v = 0; v < 4; ++v) {
        float m = sacc[0][v];
#pragma unroll
        for (int f = 1; f < 16; ++f) m = fmaxf(m, sacc[f][v]);
        m = fmaxf(m, __shfl_xor(m, 1));
        m = fmaxf(m, __shfl_xor(m, 2));
        m = fmaxf(m, __shfl_xor(m, 4));
        m = fmaxf(m, __shfl_xor(m, 8));
        float l = 0.f;
#pragma unroll
        for (int f = 0; f < 16; ++f) {
            float e = __expf(sacc[f][v] - m);
            sacc[f][v] = e;
            l += e;
        }
        l += __shfl_xor(l, 1);
        l += __shfl_xor(l, 2);
        l += __shfl_xor(l, 4);
        l += __shfl_xor(l, 8);
        inv[v] = 1.f / l;
    }

    // ---- write unnormalized P (fp16) to LDS ----
    {
        const int rb = wv * 16 + grp * 4;
#pragma unroll
        for (int f = 0; f < 16; ++f) {
            const int col = (f >> 3) * 128 + (f & 7) * 16 + frow;
#pragma unroll
            for (int v = 0; v < 4; ++v)
                Ps[(rb + v) * 264 + col] = (_Float16)sacc[f][v];
        }
    }

    // ---- PV: O[64 rows][64 d] over 2 slot-chunks of 128; V^T staged in LDS ----
    f32x4 oacc[4];
#pragma unroll
    for (int jd = 0; jd < 4; ++jd) oacc[jd] = (f32x4){0.f, 0.f, 0.f, 0.f};

#pragma unroll
    for (int c = 0; c < 2; ++c) {
        // stage V^T chunk: Vs[d][sl] (prior barrier guarantees Ks/Vs free)
        {
            const int sl = tid >> 1;
            const int d0 = (tid & 1) * 32;
            const int kg = kbase + c * 128 + sl;
            f16x8 vv[4];
            if ((unsigned)kg < (unsigned)N_) {
                const f16x8* vp = (const f16x8*)(vh + ((size_t)h * N_ + kg) * D_ + d0);
#pragma unroll
                for (int q = 0; q < 4; ++q) vv[q] = vp[q];
            } else {
#pragma unroll
                for (int q = 0; q < 4; ++q)
#pragma unroll
                    for (int e = 0; e < 8; ++e) vv[q][e] = (_Float16)0.f;
            }
#pragma unroll
            for (int q = 0; q < 4; ++q)
#pragma unroll
                for (int e = 0; e < 8; ++e)
                    Vs[(d0 + q * 8 + e) * 136 + sl] = vv[q][e];
        }
        __syncthreads();   // Ps (c==0) + Vs ready
        const int rp = wv * 16 + frow;
#pragma unroll
        for (int ks = 0; ks < 4; ++ks) {
            const f16x8 ap = *(const f16x8*)((char*)Ps + rp * 528 + c * 256 + ks * 64 + grp * 16);
#pragma unroll
            for (int jd = 0; jd < 4; ++jd) {
                const f16x8 bv = *(const f16x8*)((char*)Vs + (jd * 16 + frow) * 272 + ks * 64 + grp * 16);
                oacc[jd] = __builtin_amdgcn_mfma_f32_16x16x32_f16(ap, bv, oacc[jd], 0, 0, 0);
            }
        }
        __syncthreads();   // Vs reads done before restage
    }

    // ---- epilogue: O * inv * gate -> bf16 hi/lo ----
#pragma unroll
    for (int jd = 0; jd < 4; ++jd) {
        const int dcol = jd * 16 + frow;
        const int cg = h * 64 + dcol;
#pragma unroll
        for (int v = 0; v < 4; ++v) {
            const int n = t * 64 + wv * 16 + grp * 4 + v;
            const float gt = (float)gh[(size_t)n * HD_ + cg];
            const float val = oacc[jd][v] * inv[v] * gt;
            bf2 s = split_bf16(val);
            o_hi[(size_t)n * HD_ + cg] = s.h;
            o_lo[(size_t)n * HD_ + cg] = s.l;
        }
    }
}

// ---------------------------------------------------------------------------
// Kernel 3: out = (o*g)[4096x1024] @ Wo[1024x256] via split-bf16 MFMA.
// Tile 64x64, XCD swizzle (4 col-tiles of one row-slice share an XCD).
// ---------------------------------------------------------------------------
__global__ __launch_bounds__(256) void out_mfma(
    const __bf16* __restrict__ o_hi, const __bf16* __restrict__ o_lo,
    const __bf16* __restrict__ WoTh, const __bf16* __restrict__ WoTl,
    float* __restrict__ out)
{
    __shared__ __align__(16) __bf16 smem[4 * 2048];  // As_h, As_l, Bs_h, Bs_l (4 KB each)
    __bf16* As_h = smem;
    __bf16* As_l = smem + 2048;
    __bf16* Bs_h = smem + 4096;
    __bf16* Bs_l = smem + 6144;

    const int lb  = blockIdx.x;
    const int xcd = lb & 7;
    const int idx = lb >> 3;                 // 0..31
    const int rowg = (idx >> 2) * 8 + xcd;   // 0..63
    const int m0  = rowg * 64;
    const int c0  = (idx & 3) * 64;

    const int tid  = threadIdx.x;
    const int wave = tid >> 6;
    const int lane = tid & 63;
    const int wr   = wave >> 1;
    const int wc   = wave & 1;

    const int srow  = tid >> 2;        // 0..63
    const int selem = (tid & 3) * 8;   // 0..24
    const int sbyte = tid * 16;

    f32x4 acc[2][2];
#pragma unroll
    for (int i = 0; i < 2; ++i)
#pragma unroll
        for (int j = 0; j < 2; ++j) acc[i][j] = (f32x4){0.f, 0.f, 0.f, 0.f};

    const int frow = lane & 15;
    const int fk   = (lane >> 4) * 8;

    for (int kt = 0; kt < 1024; kt += 32) {
        __syncthreads();
        gload16(o_hi + (size_t)(m0 + srow) * HD_ + kt + selem, (char*)As_h + sbyte);
        gload16(o_lo + (size_t)(m0 + srow) * HD_ + kt + selem, (char*)As_l + sbyte);
        gload16(WoTh + (size_t)(c0 + srow) * HD_ + kt + selem, (char*)Bs_h + sbyte);
        gload16(WoTl + (size_t)(c0 + srow) * HD_ + kt + selem, (char*)Bs_l + sbyte);
        __syncthreads();

        bf16x8 afh[2], afl[2], bfh[2], bfl[2];
#pragma unroll
        for (int f = 0; f < 2; ++f) {
            const int ar = (wr * 32 + f * 16 + frow) * 32 + fk;
            const int br = (wc * 32 + f * 16 + frow) * 32 + fk;
            afh[f] = *(const bf16x8*)&As_h[ar];
            afl[f] = *(const bf16x8*)&As_l[ar];
            bfh[f] = *(const bf16x8*)&Bs_h[br];
            bfl[f] = *(const bf16x8*)&Bs_l[br];
        }
#pragma unroll
        for (int i = 0; i < 2; ++i)
#pragma unroll
            for (int j = 0; j < 2; ++j) {
                acc[i][j] = __builtin_amdgcn_mfma_f32_16x16x32_bf16(afh[i], bfh[j], acc[i][j], 0, 0, 0);
                acc[i][j] = __builtin_amdgcn_mfma_f32_16x16x32_bf16(afl[i], bfh[j], acc[i][j], 0, 0, 0);
                acc[i][j] = __builtin_amdgcn_mfma_f32_16x16x32_bf16(afh[i], bfl[j], acc[i][j], 0, 0, 0);
            }
    }

    const int rbase = (lane >> 4) * 4;
    const int colc  = lane & 15;
#pragma unroll
    for (int i = 0; i < 2; ++i)
#pragma unroll
        for (int j = 0; j < 2; ++j) {
            const int c = c0 + wc * 32 + j * 16 + colc;
#pragma unroll
            for (int v = 0; v < 4; ++v) {
                const int n = m0 + wr * 32 + i * 16 + rbase + v;
                out[(size_t)n * C_ + c] = acc[i][j][v];
            }
        }
}

// ---------------------------------------------------------------------------
extern "C" void kernel_launch(void* const* d_in, const int* in_sizes, int n_in,
                              void* d_out, int out_size, void* d_ws, size_t ws_size,
                              hipStream_t stream)
{
    const float* q_x  = (const float*)d_in[0];
    const float* kv_x = (const float*)d_in[1];
    const float* bias = (const float*)d_in[2];
    const float* Wq   = (const float*)d_in[3];
    const float* Wk   = (const float*)d_in[4];
    const float* Wv   = (const float*)d_in[5];
    const float* Wg   = (const float*)d_in[6];
    const float* Wo   = (const float*)d_in[7];
    float* out = (float*)d_out;

    // workspace layout (61 MB)
    char* ws = (char*)d_ws;
    const size_t MB = 1048576;
    _Float16* qh  = (_Float16*)(ws);             // [16][4096][64] fp16, pre-scaled 1/8
    _Float16* kh  = (_Float16*)(ws + 8  * MB);
    _Float16* vh  = (_Float16*)(ws + 16 * MB);
    _Float16* gh  = (_Float16*)(ws + 24 * MB);   // [4096][1024] fp16 sigmoid gate
    __bf16* o_hi  = (__bf16*)(ws + 32 * MB);     // [4096][1024] bf16
    __bf16* o_lo  = (__bf16*)(ws + 40 * MB);
    __bf16* Xh    = (__bf16*)(ws + 48 * MB);     // [2][4096][256]
    __bf16* Xl    = (__bf16*)(ws + 52 * MB);
    __bf16* WTh   = (__bf16*)(ws + 56 * MB);     // [4][1024][256]
    __bf16* WTl   = (__bf16*)(ws + 58 * MB);
    __bf16* WoTh  = (__bf16*)(ws + 60 * MB);     // [256][1024]
    __bf16* WoTl  = (__bf16*)(ws + 60 * MB + 524288);

    convert_kernel<<<832, 256, 0, stream>>>(q_x, kv_x, Wq, Wk, Wv, Wg, Wo,
                                            Xh, Xl, WTh, WTl, WoTh, WoTl);
    proj_mfma<<<1024, 256, 0, stream>>>(Xh, Xl, WTh, WTl, qh, kh, vh, gh);
    attn_mfma<<<1024, 256, 0, stream>>>(qh, kh, vh, bias, gh, o_hi, o_lo);
    out_mfma<<<256, 256, 0, stream>>>(o_hi, o_lo, WoTh, WoTl, out);
}

// Round 7
// 173.319 us; speedup vs baseline: 1.1362x; 1.1362x over previous
//
#include <hip/hip_runtime.h>

#define N_ 4096
#define C_ 256
#define H_ 16
#define D_ 64
#define HD_ 1024

typedef __attribute__((ext_vector_type(8))) __bf16 bf16x8;
typedef __attribute__((ext_vector_type(4))) __bf16 bf16x4;
typedef __attribute__((ext_vector_type(8))) _Float16 f16x8;
typedef __attribute__((ext_vector_type(4))) _Float16 f16x4;
typedef __attribute__((ext_vector_type(4))) float f32x4;

__device__ __forceinline__ void gload16(const void* g, void* l) {
    __builtin_amdgcn_global_load_lds(
        (const __attribute__((address_space(1))) unsigned int*)g,
        (__attribute__((address_space(3))) unsigned int*)l, 16, 0, 0);
}

struct bf2 { __bf16 h, l; };
__device__ __forceinline__ bf2 split_bf16(float v) {
    bf2 r;
    r.h = (__bf16)v;
    r.l = (__bf16)(v - (float)r.h);
    return r;
}

// ---------------------------------------------------------------------------
// Kernel 0: convert fp32 inputs. X, Wq..Wg -> fp16; Wo -> bf16 hi/lo.
// W transposed K-contiguous.
// ---------------------------------------------------------------------------
__global__ __launch_bounds__(256) void convert_kernel(
    const float* __restrict__ q_x, const float* __restrict__ kv_x,
    const float* __restrict__ Wq, const float* __restrict__ Wk,
    const float* __restrict__ Wv, const float* __restrict__ Wg,
    const float* __restrict__ Wo,
    _Float16* __restrict__ Xf, _Float16* __restrict__ WTf,
    __bf16* __restrict__ WoTh, __bf16* __restrict__ WoTl)
{
    __shared__ float ts[64][65];
    const int b = blockIdx.x;
    const int tid = threadIdx.x;

    if (b < 512) {
        const int seg = b >> 8;
        const float* src = seg ? kv_x : q_x;
        _Float16* df = Xf + (size_t)seg * 1048576;
        const int base = (b & 255) * 4096 + tid * 16;
#pragma unroll
        for (int q = 0; q < 4; ++q) {
            float4 v = *(const float4*)&src[base + q * 4];
            f16x4 fv;
            fv[0] = (_Float16)v.x; fv[1] = (_Float16)v.y;
            fv[2] = (_Float16)v.z; fv[3] = (_Float16)v.w;
            *(f16x4*)&df[base + q * 4] = fv;
        }
        return;
    }

    if (b < 768) {
        // W transpose -> fp16
        const int widx = (b - 512) >> 6;
        const int tile = (b - 512) & 63;
        const float* src = (widx == 0) ? Wq : (widx == 1) ? Wk : (widx == 2) ? Wv : Wg;
        _Float16* df = WTf + (size_t)widx * 262144;
        const int r0 = (tile >> 4) * 64;      // rows of 256
        const int c0 = (tile & 15) * 64;      // cols of 1024
        {
            const int r = tid >> 2;
            const int cch = (tid & 3) * 16;
#pragma unroll
            for (int q = 0; q < 4; ++q) {
                float4 v = *(const float4*)&src[(size_t)(r0 + r) * 1024 + c0 + cch + q * 4];
                ts[r][cch + q * 4 + 0] = v.x;
                ts[r][cch + q * 4 + 1] = v.y;
                ts[r][cch + q * 4 + 2] = v.z;
                ts[r][cch + q * 4 + 3] = v.w;
            }
        }
        __syncthreads();
        {
            const int c = tid >> 2;
            const int rch = (tid & 3) * 16;
#pragma unroll
            for (int q = 0; q < 4; ++q) {
                f16x4 fv;
#pragma unroll
                for (int j = 0; j < 4; ++j)
                    fv[j] = (_Float16)ts[rch + q * 4 + j][c];
                *(f16x4*)&df[(size_t)(c0 + c) * 256 + r0 + rch + q * 4] = fv;
            }
        }
        return;
    }

    // Wo transpose -> bf16 hi/lo
    {
        const int tile = b - 768;
        const int r0 = (tile >> 2) * 64;      // rows of 1024
        const int c0 = (tile & 3) * 64;       // cols of 256
        {
            const int r = tid >> 2;
            const int cch = (tid & 3) * 16;
#pragma unroll
            for (int q = 0; q < 4; ++q) {
                float4 v = *(const float4*)&Wo[(size_t)(r0 + r) * 256 + c0 + cch + q * 4];
                ts[r][cch + q * 4 + 0] = v.x;
                ts[r][cch + q * 4 + 1] = v.y;
                ts[r][cch + q * 4 + 2] = v.z;
                ts[r][cch + q * 4 + 3] = v.w;
            }
        }
        __syncthreads();
        {
            const int c = tid >> 2;
            const int rch = (tid & 3) * 16;
#pragma unroll
            for (int q = 0; q < 4; ++q) {
                bf16x4 hv, lv;
#pragma unroll
                for (int j = 0; j < 4; ++j) {
                    bf2 s = split_bf16(ts[rch + q * 4 + j][c]);
                    hv[j] = s.h; lv[j] = s.l;
                }
                *(bf16x4*)&WoTh[(size_t)(c0 + c) * 1024 + r0 + rch + q * 4] = hv;
                *(bf16x4*)&WoTl[(size_t)(c0 + c) * 1024 + r0 + rch + q * 4] = lv;
            }
        }
    }
}

// ---------------------------------------------------------------------------
// Kernel 1: projections via plain fp16 MFMA. 4 GEMMs M=4096,N=1024,K=256.
// 128x128 tile, BK=64 (full 128B rows). XOR-8 chunk swizzle.
// Staging: tile = 128 rows x 128 B = 16 KB = 4 chunks/thread:
//   row = p*32 + (tid>>3), ch = tid&7, LDS byte = row*128 + ch*16
//   = p*4096 + tid*16, p in 0..3.   (R6 bug: p<2 with p*8192 left half
//   the tile uninitialized -> NaN.)
// ---------------------------------------------------------------------------
__global__ __launch_bounds__(256) void proj_mfma(
    const _Float16* __restrict__ Xf, const _Float16* __restrict__ WTf,
    _Float16* __restrict__ qh, _Float16* __restrict__ kh,
    _Float16* __restrict__ vh, _Float16* __restrict__ gh)
{
    __shared__ __align__(16) _Float16 smem[2 * 8192];   // As, Bs: [128][64] 16KB each
    _Float16* As = smem;
    _Float16* Bs = smem + 8192;

    // XCD-aware remap: all 8 col-tiles of one (g,row-tile) share xcd = lb&7
    const int lb  = blockIdx.x;
    const int xcd = lb & 7;
    const int gr  = (lb >> 6) * 8 + xcd;    // 0..127 -> (g, row-tile)
    const int g   = gr >> 5;
    const int m0  = (gr & 31) * 128;
    const int c0  = ((lb >> 3) & 7) * 128;

    const _Float16* A = Xf + ((g == 1 || g == 2) ? 1048576 : 0);
    const _Float16* B = WTf + (size_t)g * 262144;

    const int tid  = threadIdx.x;
    const int wave = tid >> 6;
    const int lane = tid & 63;
    const int wr   = wave >> 1;
    const int wc   = wave & 1;
    const int frow = lane & 15;
    const int grp  = lane >> 4;

    f32x4 acc[4][4];
#pragma unroll
    for (int i = 0; i < 4; ++i)
#pragma unroll
        for (int j = 0; j < 4; ++j) acc[i][j] = (f32x4){0.f, 0.f, 0.f, 0.f};

    const int srow = tid >> 3;              // 0..31
    const int sch  = tid & 7;               // chunk 0..7

    for (int kt = 0; kt < 256; kt += 64) {
        __syncthreads();
#pragma unroll
        for (int p = 0; p < 4; ++p) {
            const int row = p * 32 + srow;
            const int koff = kt + ((sch ^ (row & 7)) << 3);
            gload16(A + (size_t)(m0 + row) * 256 + koff, (char*)As + p * 4096 + tid * 16);
            gload16(B + (size_t)(c0 + row) * 256 + koff, (char*)Bs + p * 4096 + tid * 16);
        }
        __syncthreads();

#pragma unroll
        for (int ks = 0; ks < 2; ++ks) {
            f16x8 af[4], bf[4];
#pragma unroll
            for (int f = 0; f < 4; ++f) {
                const int ra = wr * 64 + f * 16 + frow;
                const int rb = wc * 64 + f * 16 + frow;
                af[f] = *(const f16x8*)((char*)As + ra * 128 + (((ks * 4 + grp) ^ (ra & 7)) << 4));
                bf[f] = *(const f16x8*)((char*)Bs + rb * 128 + (((ks * 4 + grp) ^ (rb & 7)) << 4));
            }
#pragma unroll
            for (int i = 0; i < 4; ++i)
#pragma unroll
                for (int j = 0; j < 4; ++j)
                    acc[i][j] = __builtin_amdgcn_mfma_f32_16x16x32_f16(af[i], bf[j], acc[i][j], 0, 0, 0);
        }
    }

    // epilogue: C/D layout col=lane&15, row=(lane>>4)*4+reg [m89]
    const int rbase = grp * 4;
    if (g == 3) {
#pragma unroll
        for (int i = 0; i < 4; ++i)
#pragma unroll
            for (int j = 0; j < 4; ++j) {
                const int c = c0 + wc * 64 + j * 16 + frow;
#pragma unroll
                for (int v = 0; v < 4; ++v) {
                    const int n = m0 + wr * 64 + i * 16 + rbase + v;
                    gh[(size_t)n * HD_ + c] = (_Float16)(1.f / (1.f + __expf(-acc[i][j][v])));
                }
            }
    } else {
        const float scale = (g == 0) ? 0.125f : 1.f;
        _Float16* dst = (g == 0) ? qh : (g == 1) ? kh : vh;
#pragma unroll
        for (int i = 0; i < 4; ++i)
#pragma unroll
            for (int j = 0; j < 4; ++j) {
                const int c = c0 + wc * 64 + j * 16 + frow;
                const int hh = c >> 6, dd = c & 63;
#pragma unroll
                for (int v = 0; v < 4; ++v) {
                    const int n = m0 + wr * 64 + i * 16 + rbase + v;
                    dst[((size_t)hh * N_ + n) * D_ + dd] = (_Float16)(acc[i][j][v] * scale);
                }
            }
    }
}

// ---------------------------------------------------------------------------
// Kernel 2: local attention via fp16 MFMA. One block per (h,t), 4 waves.
// XCD swizzle: trunks t in [8*xcd, 8*xcd+8) x all heads on one XCD.
// ---------------------------------------------------------------------------
__global__ __launch_bounds__(256) void attn_mfma(
    const _Float16* __restrict__ qh, const _Float16* __restrict__ kh,
    const _Float16* __restrict__ vh, const float* __restrict__ bias,
    const _Float16* __restrict__ gh,
    __bf16* __restrict__ o_hi, __bf16* __restrict__ o_lo)
{
    __shared__ __align__(16) char smem[59392];
    _Float16* Qs = (_Float16*)smem;              // [64][64], swizzled chunks, 8 KB
    char* Ks = smem + 8192;                      // K: [128][64] swizzled, 16 KB
    _Float16* Vs = (_Float16*)(smem + 8192);     // V^T: [64][136], 17408 B (overlays Ks)
    _Float16* Ps = (_Float16*)(smem + 25600);    // [64][264], 33792 B

    const int lb  = blockIdx.x;
    const int xcd = lb & 7;
    const int j_  = lb >> 3;
    const int h   = j_ >> 3;                // 0..15
    const int t   = xcd * 8 + (j_ & 7);     // 0..63, 8 consecutive t per XCD
    const int tid = threadIdx.x;
    const int lane = tid & 63;
    const int wv = tid >> 6;
    const int frow = lane & 15;
    const int grp = lane >> 4;
    const int kbase = t * 64 - 96;

    const char* qbase = (const char*)qh + (size_t)(h * N_ + t * 64) * 128;
    const char* kbase_p = (const char*)kh + (size_t)h * N_ * 128;

    // ---- stage Q (8 KB, always in-bounds), issue async ----
#pragma unroll
    for (int q = 0; q < 2; ++q) {
        const int lin = q * 4096 + tid * 16;
        const int row = lin >> 7;
        const int ch = (lin >> 4) & 7;
        gload16(qbase + row * 128 + ((ch ^ (row & 7)) << 4), (char*)Qs + lin);
    }

    f32x4 sacc[16];

#pragma unroll
    for (int p = 0; p < 2; ++p) {
        // stage K chunk p (16 KB); OOB rows -> zero (wave-uniform split)
#pragma unroll
        for (int q = 0; q < 4; ++q) {
            const int lin = q * 4096 + tid * 16;
            const int row = lin >> 7;
            const int ch = (lin >> 4) & 7;
            const int kg = kbase + p * 128 + row;
            if ((unsigned)kg < (unsigned)N_) {
                gload16(kbase_p + (size_t)kg * 128 + ((ch ^ (row & 7)) << 4), Ks + lin);
            } else {
                *(float4*)(Ks + lin) = make_float4(0.f, 0.f, 0.f, 0.f);
            }
        }
        // bias -> accumulator init for this chunk
        {
            const int rowg = t * 64 + wv * 16 + grp * 4;
#pragma unroll
            for (int j = 0; j < 8; ++j) {
                const int colg = kbase + p * 128 + j * 16 + frow;
                const bool ok = (unsigned)colg < (unsigned)N_;
#pragma unroll
                for (int v = 0; v < 4; ++v)
                    sacc[p * 8 + j][v] = ok ? bias[(size_t)(rowg + v) * N_ + colg] : 0.f;
            }
        }
        __syncthreads();   // staging complete (Q covered at p=0)
        const int rq = wv * 16 + frow;
#pragma unroll
        for (int ks = 0; ks < 2; ++ks) {
            const f16x8 aq = *(const f16x8*)((char*)Qs + rq * 128 + (((ks * 4 + grp) ^ (rq & 7)) << 4));
#pragma unroll
            for (int j = 0; j < 8; ++j) {
                const int rk = j * 16 + frow;
                const f16x8 bk = *(const f16x8*)(Ks + rk * 128 + (((ks * 4 + grp) ^ (rk & 7)) << 4));
                sacc[p * 8 + j] = __builtin_amdgcn_mfma_f32_16x16x32_f16(aq, bk, sacc[p * 8 + j], 0, 0, 0);
            }
        }
        __syncthreads();   // K reads done before restage/overlay
    }

    // ---- softmax over 256 slots/row; rows owned per (grp, v) ----
    float inv[4];
#pragma unroll
    for (int v = 0; v < 4; ++v) {
        float m = sacc[0][v];
#pragma unroll
        for (int f = 1; f < 16; ++f) m = fmaxf(m, sacc[f][v]);
        m = fmaxf(m, __shfl_xor(m, 1));
        m = fmaxf(m, __shfl_xor(m, 2));
        m = fmaxf(m, __shfl_xor(m, 4));
        m = fmaxf(m, __shfl_xor(m, 8));
        float l = 0.f;
#pragma unroll
        for (int f = 0; f < 16; ++f) {
            float e = __expf(sacc[f][v] - m);
            sacc[f][v] = e;
            l += e;
        }
        l += __shfl_xor(l, 1);
        l += __shfl_xor(l, 2);
        l += __shfl_xor(l, 4);
        l += __shfl_xor(l, 8);
        inv[v] = 1.f / l;
    }

    // ---- write unnormalized P (fp16) to LDS ----
    {
        const int rb = wv * 16 + grp * 4;
#pragma unroll
        for (int f = 0; f < 16; ++f) {
            const int col = (f >> 3) * 128 + (f & 7) * 16 + frow;
#pragma unroll
            for (int v = 0; v < 4; ++v)
                Ps[(rb + v) * 264 + col] = (_Float16)sacc[f][v];
        }
    }

    // ---- PV: O[64 rows][64 d] over 2 slot-chunks of 128; V^T staged in LDS ----
    f32x4 oacc[4];
#pragma unroll
    for (int jd = 0; jd < 4; ++jd) oacc[jd] = (f32x4){0.f, 0.f, 0.f, 0.f};

#pragma unroll
    for (int c = 0; c < 2; ++c) {
        // stage V^T chunk: Vs[d][sl] (prior barrier guarantees Ks/Vs free)
        {
            const int sl = tid >> 1;
            const int d0 = (tid & 1) * 32;
            const int kg = kbase + c * 128 + sl;
            f16x8 vv[4];
            if ((unsigned)kg < (unsigned)N_) {
                const f16x8* vp = (const f16x8*)(vh + ((size_t)h * N_ + kg) * D_ + d0);
#pragma unroll
                for (int q = 0; q < 4; ++q) vv[q] = vp[q];
            } else {
#pragma unroll
                for (int q = 0; q < 4; ++q)
#pragma unroll
                    for (int e = 0; e < 8; ++e) vv[q][e] = (_Float16)0.f;
            }
#pragma unroll
            for (int q = 0; q < 4; ++q)
#pragma unroll
                for (int e = 0; e < 8; ++e)
                    Vs[(d0 + q * 8 + e) * 136 + sl] = vv[q][e];
        }
        __syncthreads();   // Ps (c==0) + Vs ready
        const int rp = wv * 16 + frow;
#pragma unroll
        for (int ks = 0; ks < 4; ++ks) {
            const f16x8 ap = *(const f16x8*)((char*)Ps + rp * 528 + c * 256 + ks * 64 + grp * 16);
#pragma unroll
            for (int jd = 0; jd < 4; ++jd) {
                const f16x8 bv = *(const f16x8*)((char*)Vs + (jd * 16 + frow) * 272 + ks * 64 + grp * 16);
                oacc[jd] = __builtin_amdgcn_mfma_f32_16x16x32_f16(ap, bv, oacc[jd], 0, 0, 0);
            }
        }
        __syncthreads();   // Vs reads done before restage
    }

    // ---- epilogue: O * inv * gate -> bf16 hi/lo ----
#pragma unroll
    for (int jd = 0; jd < 4; ++jd) {
        const int dcol = jd * 16 + frow;
        const int cg = h * 64 + dcol;
#pragma unroll
        for (int v = 0; v < 4; ++v) {
            const int n = t * 64 + wv * 16 + grp * 4 + v;
            const float gt = (float)gh[(size_t)n * HD_ + cg];
            const float val = oacc[jd][v] * inv[v] * gt;
            bf2 s = split_bf16(val);
            o_hi[(size_t)n * HD_ + cg] = s.h;
            o_lo[(size_t)n * HD_ + cg] = s.l;
        }
    }
}

// ---------------------------------------------------------------------------
// Kernel 3: out = (o*g)[4096x1024] @ Wo[1024x256] via split-bf16 MFMA.
// Tile 64x64, XCD swizzle (4 col-tiles of one row-slice share an XCD).
// ---------------------------------------------------------------------------
__global__ __launch_bounds__(256) void out_mfma(
    const __bf16* __restrict__ o_hi, const __bf16* __restrict__ o_lo,
    const __bf16* __restrict__ WoTh, const __bf16* __restrict__ WoTl,
    float* __restrict__ out)
{
    __shared__ __align__(16) __bf16 smem[4 * 2048];  // As_h, As_l, Bs_h, Bs_l (4 KB each)
    __bf16* As_h = smem;
    __bf16* As_l = smem + 2048;
    __bf16* Bs_h = smem + 4096;
    __bf16* Bs_l = smem + 6144;

    const int lb  = blockIdx.x;
    const int xcd = lb & 7;
    const int idx = lb >> 3;                 // 0..31
    const int rowg = (idx >> 2) * 8 + xcd;   // 0..63
    const int m0  = rowg * 64;
    const int c0  = (idx & 3) * 64;

    const int tid  = threadIdx.x;
    const int wave = tid >> 6;
    const int lane = tid & 63;
    const int wr   = wave >> 1;
    const int wc   = wave & 1;

    const int srow  = tid >> 2;        // 0..63
    const int selem = (tid & 3) * 8;   // 0..24
    const int sbyte = tid * 16;

    f32x4 acc[2][2];
#pragma unroll
    for (int i = 0; i < 2; ++i)
#pragma unroll
        for (int j = 0; j < 2; ++j) acc[i][j] = (f32x4){0.f, 0.f, 0.f, 0.f};

    const int frow = lane & 15;
    const int fk   = (lane >> 4) * 8;

    for (int kt = 0; kt < 1024; kt += 32) {
        __syncthreads();
        gload16(o_hi + (size_t)(m0 + srow) * HD_ + kt + selem, (char*)As_h + sbyte);
        gload16(o_lo + (size_t)(m0 + srow) * HD_ + kt + selem, (char*)As_l + sbyte);
        gload16(WoTh + (size_t)(c0 + srow) * HD_ + kt + selem, (char*)Bs_h + sbyte);
        gload16(WoTl + (size_t)(c0 + srow) * HD_ + kt + selem, (char*)Bs_l + sbyte);
        __syncthreads();

        bf16x8 afh[2], afl[2], bfh[2], bfl[2];
#pragma unroll
        for (int f = 0; f < 2; ++f) {
            const int ar = (wr * 32 + f * 16 + frow) * 32 + fk;
            const int br = (wc * 32 + f * 16 + frow) * 32 + fk;
            afh[f] = *(const bf16x8*)&As_h[ar];
            afl[f] = *(const bf16x8*)&As_l[ar];
            bfh[f] = *(const bf16x8*)&Bs_h[br];
            bfl[f] = *(const bf16x8*)&Bs_l[br];
        }
#pragma unroll
        for (int i = 0; i < 2; ++i)
#pragma unroll
            for (int j = 0; j < 2; ++j) {
                acc[i][j] = __builtin_amdgcn_mfma_f32_16x16x32_bf16(afh[i], bfh[j], acc[i][j], 0, 0, 0);
                acc[i][j] = __builtin_amdgcn_mfma_f32_16x16x32_bf16(afl[i], bfh[j], acc[i][j], 0, 0, 0);
                acc[i][j] = __builtin_amdgcn_mfma_f32_16x16x32_bf16(afh[i], bfl[j], acc[i][j], 0, 0, 0);
            }
    }

    const int rbase = (lane >> 4) * 4;
    const int colc  = lane & 15;
#pragma unroll
    for (int i = 0; i < 2; ++i)
#pragma unroll
        for (int j = 0; j < 2; ++j) {
            const int c = c0 + wc * 32 + j * 16 + colc;
#pragma unroll
            for (int v = 0; v < 4; ++v) {
                const int n = m0 + wr * 32 + i * 16 + rbase + v;
                out[(size_t)n * C_ + c] = acc[i][j][v];
            }
        }
}

// ---------------------------------------------------------------------------
extern "C" void kernel_launch(void* const* d_in, const int* in_sizes, int n_in,
                              void* d_out, int out_size, void* d_ws, size_t ws_size,
                              hipStream_t stream)
{
    const float* q_x  = (const float*)d_in[0];
    const float* kv_x = (const float*)d_in[1];
    const float* bias = (const float*)d_in[2];
    const float* Wq   = (const float*)d_in[3];
    const float* Wk   = (const float*)d_in[4];
    const float* Wv   = (const float*)d_in[5];
    const float* Wg   = (const float*)d_in[6];
    const float* Wo   = (const float*)d_in[7];
    float* out = (float*)d_out;

    // workspace layout (~56 MB)
    char* ws = (char*)d_ws;
    const size_t MB = 1048576;
    _Float16* qh  = (_Float16*)(ws);             // [16][4096][64] fp16, pre-scaled 1/8
    _Float16* kh  = (_Float16*)(ws + 8  * MB);
    _Float16* vh  = (_Float16*)(ws + 16 * MB);
    _Float16* gh  = (_Float16*)(ws + 24 * MB);   // [4096][1024] fp16 sigmoid gate
    __bf16* o_hi  = (__bf16*)(ws + 32 * MB);     // [4096][1024] bf16
    __bf16* o_lo  = (__bf16*)(ws + 40 * MB);
    _Float16* Xf  = (_Float16*)(ws + 48 * MB);   // [2][4096][256] fp16
    _Float16* WTf = (_Float16*)(ws + 52 * MB);   // [4][1024][256] fp16
    __bf16* WoTh  = (__bf16*)(ws + 54 * MB);     // [256][1024]
    __bf16* WoTl  = (__bf16*)(ws + 54 * MB + 524288);

    convert_kernel<<<832, 256, 0, stream>>>(q_x, kv_x, Wq, Wk, Wv, Wg, Wo,
                                            Xf, WTf, WoTh, WoTl);
    proj_mfma<<<1024, 256, 0, stream>>>(Xf, WTf, qh, kh, vh, gh);
    attn_mfma<<<1024, 256, 0, stream>>>(qh, kh, vh, bias, gh, o_hi, o_lo);
    out_mfma<<<256, 256, 0, stream>>>(o_hi, o_lo, WoTh, WoTl, out);
}